// Round 6
// baseline (3276.064 us; speedup 1.0000x reference)
//
#include <hip/hip_runtime.h>
#include <cstdint>
#include <cstddef>

#define BN 64
#define TN 512
#define DN 256
#define UN 256
#define NC 768            // 3*UN, order: r | z | h
#define SLOTS (TN + 4)    // slots TN..TN+3 = initial states
#define LO_SCL 9.765625e-4f   // 1/1024: lo-residuals stored x1024

typedef _Float16 half2_t __attribute__((ext_vector_type(2)));

__device__ __forceinline__ float sigm(float x) { return 1.0f / (1.0f + __expf(-x)); }
__device__ __forceinline__ float tanh_fast(float x) {
  float e = __expf(-2.0f * x);
  return 2.0f / (1.0f + e) - 1.0f;
}

__device__ __forceinline__ float dot2(half2_t w, half2_t x, float c) {
#if __has_builtin(__builtin_amdgcn_fdot2)
  return __builtin_amdgcn_fdot2(w, x, c, false);
#else
  return fmaf((float)w.y, (float)x.y, fmaf((float)w.x, (float)x.x, c));
#endif
}
__device__ __forceinline__ half2_t h2cast(unsigned v) { return __builtin_bit_cast(half2_t, v); }

// decode 2 e5m2 bytes (16-bit half of dw, compile-time selected) into half2.
// Exact: e5m2 and fp16 share the 5-bit exponent, so fp16 bits = e5m2 byte << 8.
template <bool HI>
__device__ __forceinline__ half2_t bf8x2_to_h2(unsigned dw) {
  unsigned s = HI ? (dw >> 16) : dw;
  unsigned h2 = ((s & 0xFFu) << 8) | ((s & 0xFF00u) << 16);
  return h2cast(h2);
}

// encode two floats to e5m2 bytes (manual RNE via fp16; deterministic, no builtins)
__device__ __forceinline__ unsigned short bf8x2_enc(float a, float b) {
  unsigned short ra, rb;
  {
    unsigned short hb = __builtin_bit_cast(unsigned short, (_Float16)a);
    unsigned m = hb & 0x7FFFu, s = hb & 0x8000u;
    unsigned r1 = m + 0x7Fu + ((m >> 8) & 1u);           // RNE 10->2 mantissa bits
    ra = (unsigned short)(((s | (r1 & 0x7F00u)) >> 8) & 0xFFu);
  }
  {
    unsigned short hb = __builtin_bit_cast(unsigned short, (_Float16)b);
    unsigned m = hb & 0x7FFFu, s = hb & 0x8000u;
    unsigned r1 = m + 0x7Fu + ((m >> 8) & 1u);
    rb = (unsigned short)(((s | (r1 & 0x7F00u)) >> 8) & 0xFFu);
  }
  return (unsigned short)(ra | (rb << 8));
}

// 3-term dot for one j (4 cols): hi*xh + hi*xl (into AH) and lo*xh (into AL, x1024-scaled)
#define DOT_J(WHI, XH, XL, D0, D1, AH, AL, J)                                                  \
  { half2_t _wl;                                                                               \
    _wl = bf8x2_to_h2<false>(D0); AH[0] = dot2(WHI[0][J], XH, AH[0]); AH[0] = dot2(WHI[0][J], XL, AH[0]); AL[0] = dot2(_wl, XH, AL[0]); \
    _wl = bf8x2_to_h2<true >(D0); AH[1] = dot2(WHI[1][J], XH, AH[1]); AH[1] = dot2(WHI[1][J], XL, AH[1]); AL[1] = dot2(_wl, XH, AL[1]); \
    _wl = bf8x2_to_h2<false>(D1); AH[2] = dot2(WHI[2][J], XH, AH[2]); AH[2] = dot2(WHI[2][J], XL, AH[2]); AL[2] = dot2(_wl, XH, AL[2]); \
    _wl = bf8x2_to_h2<true >(D1); AH[3] = dot2(WHI[3][J], XH, AH[3]); AH[3] = dot2(WHI[3][J], XL, AH[3]); AL[3] = dot2(_wl, XH, AL[3]); }

// same but lo comes as two uint2 of packed fp16 pairs (Uh-lo from LDS)
#define DOT_J_H(WHI, XH, XL, W01, W23, AH, AL, J)                                              \
  { AH[0] = dot2(WHI[0][J], XH, AH[0]); AH[0] = dot2(WHI[0][J], XL, AH[0]); AL[0] = dot2(h2cast(W01.x), XH, AL[0]); \
    AH[1] = dot2(WHI[1][J], XH, AH[1]); AH[1] = dot2(WHI[1][J], XL, AH[1]); AL[1] = dot2(h2cast(W01.y), XH, AL[1]); \
    AH[2] = dot2(WHI[2][J], XH, AH[2]); AH[2] = dot2(WHI[2][J], XL, AH[2]); AL[2] = dot2(h2cast(W23.x), XH, AL[2]); \
    AH[3] = dot2(WHI[3][J], XH, AH[3]); AH[3] = dot2(WHI[3][J], XL, AH[3]); AL[3] = dot2(h2cast(W23.y), XH, AL[3]); }

// ---------------- kernel 0: concat weights + biases (for the GEMM) ----------------
__global__ __launch_bounds__(256) void build_wcat(
    const float* __restrict__ Wr, const float* __restrict__ Wz, const float* __restrict__ Wh,
    const float* __restrict__ br, const float* __restrict__ bz, const float* __restrict__ bh,
    float* __restrict__ wcat, float* __restrict__ bias)
{
  int idx = blockIdx.x * 256 + threadIdx.x;
  if (idx < DN * NC) {
    int k = idx / NC, c = idx % NC;
    float v;
    if (c < 256)      v = Wr[k * UN + c];
    else if (c < 512) v = Wz[k * UN + (c - 256)];
    else              v = Wh[k * UN + (c - 512)];
    wcat[idx] = v;
  }
  if (idx < NC) {
    bias[idx] = (idx < 256) ? br[idx] : ((idx < 512) ? bz[idx - 256] : bh[idx - 512]);
  }
}

// ---------------- kernel 0b: hi fp16 pair pack (cc-major per-thread layout) --------
__global__ __launch_bounds__(256) void build_wpk(
    const float* __restrict__ Uh, const float* __restrict__ Ur, const float* __restrict__ Uz,
    unsigned* __restrict__ Wpk)
{
  int idx = blockIdx.x * 256 + threadIdx.x;   // 98304 total
  int j  = idx & 15;
  int mc = (idx >> 4) % 12;
  int t  = idx / 192;
  int m  = mc >> 2, cc = mc & 3;
  int q  = t >> 6, l = t & 63;
  int k  = 32 * q + 2 * j;
  int u  = 4 * l + cc;
  const float* U = (m == 0) ? Uh : ((m == 1) ? Ur : Uz);
  _Float16 lo = (_Float16)U[(size_t)k * UN + u];
  _Float16 hi = (_Float16)U[(size_t)(k + 1) * UN + u];
  Wpk[idx] = (unsigned)__builtin_bit_cast(unsigned short, lo)
           | ((unsigned)__builtin_bit_cast(unsigned short, hi) << 16);
}

// ---------------- kernel 0c: lo residuals (x1024), j-major pair order --------------
// Uh-lo -> fp16 pairs, WloH[((p>>1)*512 + t)*2 + (p&1)]
// Ur/Uz-lo -> e5m2 pairs, ushort at dword ((mm*8 + (p>>3))*512 + t)*4 + ((p&7)>>1), half p&1
__global__ __launch_bounds__(256) void build_wlo(
    const float* __restrict__ Uh, const float* __restrict__ Ur, const float* __restrict__ Uz,
    unsigned* __restrict__ WloH, unsigned short* __restrict__ WloRZ16)
{
  int idx = blockIdx.x * 256 + threadIdx.x;   // 98304 total
  int p  = idx & 63;
  int m  = (idx >> 6) % 3;
  int t  = idx / 192;
  int q = t >> 6, l = t & 63;
  int j = p >> 2, cc = p & 3;
  int k = 32 * q + 2 * j, u = 4 * l + cc;
  const float* U = (m == 0) ? Uh : ((m == 1) ? Ur : Uz);
  float w0 = U[(size_t)k * UN + u], w1 = U[(size_t)(k + 1) * UN + u];
  _Float16 h0 = (_Float16)w0, h1 = (_Float16)w1;
  float l0 = (w0 - (float)h0) * 1024.0f, l1 = (w1 - (float)h1) * 1024.0f;
  if (m == 0) {
    half2_t lp;
    lp.x = (_Float16)l0; lp.y = (_Float16)l1;
    WloH[((p >> 1) * 512 + t) * 2 + (p & 1)] = __builtin_bit_cast(unsigned, lp);
  } else {
    int mm = m - 1;
    WloRZ16[(((mm * 8 + (p >> 3)) * 512 + t) * 4 + ((p & 7) >> 1)) * 2 + (p & 1)] = bf8x2_enc(l0, l1);
  }
}

// ---------------- kernel 1: P = X @ Wcat + bias  (fp32, LDS-tiled) ----------------
__global__ __launch_bounds__(256) void gemm_xw(
    const float* __restrict__ X, const float* __restrict__ Wc,
    const float* __restrict__ bias, float* __restrict__ P)
{
  __shared__ float As[32][68];
  __shared__ float Bs[32][64];
  const int tid = threadIdx.x;
  const int m0 = blockIdx.x * 64;
  const int n0 = blockIdx.y * 64;
  const int ty = tid >> 4, tx = tid & 15;
  float acc[4][4] = {};

  const int ar = tid >> 3;
  const int ak = (tid & 7) * 4;
  const int bk = tid >> 4;
  const int bn = (tid & 15) * 4;

  for (int k0 = 0; k0 < DN; k0 += 32) {
    float4 a0 = *(const float4*)(X + (size_t)(m0 + ar) * DN + k0 + ak);
    float4 a1 = *(const float4*)(X + (size_t)(m0 + 32 + ar) * DN + k0 + ak);
    As[ak + 0][ar] = a0.x; As[ak + 1][ar] = a0.y; As[ak + 2][ar] = a0.z; As[ak + 3][ar] = a0.w;
    As[ak + 0][32 + ar] = a1.x; As[ak + 1][32 + ar] = a1.y; As[ak + 2][32 + ar] = a1.z; As[ak + 3][32 + ar] = a1.w;
    *(float4*)&Bs[bk][bn]      = *(const float4*)(Wc + (size_t)(k0 + bk) * NC + n0 + bn);
    *(float4*)&Bs[bk + 16][bn] = *(const float4*)(Wc + (size_t)(k0 + bk + 16) * NC + n0 + bn);
    __syncthreads();
#pragma unroll
    for (int kk = 0; kk < 32; kk++) {
      float4 av = *(const float4*)&As[kk][ty * 4];
      float4 bv = *(const float4*)&Bs[kk][tx * 4];
      acc[0][0] += av.x * bv.x; acc[0][1] += av.x * bv.y; acc[0][2] += av.x * bv.z; acc[0][3] += av.x * bv.w;
      acc[1][0] += av.y * bv.x; acc[1][1] += av.y * bv.y; acc[1][2] += av.y * bv.z; acc[1][3] += av.y * bv.w;
      acc[2][0] += av.z * bv.x; acc[2][1] += av.z * bv.y; acc[2][2] += av.z * bv.z; acc[2][3] += av.z * bv.w;
      acc[3][0] += av.w * bv.x; acc[3][1] += av.w * bv.y; acc[3][2] += av.w * bv.z; acc[3][3] += av.w * bv.w;
    }
    __syncthreads();
  }
  float4 bb = *(const float4*)(bias + n0 + tx * 4);
#pragma unroll
  for (int i = 0; i < 4; i++) {
    float4 o;
    o.x = acc[i][0] + bb.x; o.y = acc[i][1] + bb.y;
    o.z = acc[i][2] + bb.z; o.w = acc[i][3] + bb.w;
    *(float4*)(P + (size_t)(m0 + ty * 4 + i) * NC + n0 + tx * 4) = o;
  }
}

// -------- Ur+Uz projection: hi regs + bf8-lo streamed from L2, 3-term compensated ---
__device__ __forceinline__ void proj_rz(
    int tid, int q, int u0,
    const unsigned* xh_ls, const unsigned* xl_ls,
    const half2_t (&wr)[4][16], const half2_t (&wz)[4][16],
    const uint4* __restrict__ WloRZ,
    float (*redR)[256], float (*redZ)[256])
{
  {
    float ah[4] = {0, 0, 0, 0}, al[4] = {0, 0, 0, 0};
    const uint4* WL = WloRZ + tid;          // Ur groups: [g*512]
    uint4 cb[4];
#pragma unroll
    for (int i = 0; i < 4; i++) cb[i] = WL[i * 512];
#pragma unroll
    for (int g = 0; g < 8; g++) {
      uint4 cur = cb[g & 3];
      if (g < 4) cb[g & 3] = WL[(g + 4) * 512];
      uint2 x2h = *(const uint2*)&xh_ls[16 * q + 2 * g];
      uint2 x2l = *(const uint2*)&xl_ls[16 * q + 2 * g];
      DOT_J(wr, h2cast(x2h.x), h2cast(x2l.x), cur.x, cur.y, ah, al, 2 * g);
      DOT_J(wr, h2cast(x2h.y), h2cast(x2l.y), cur.z, cur.w, ah, al, 2 * g + 1);
    }
    *(float4*)&redR[q][u0] = make_float4(ah[0] + al[0] * LO_SCL, ah[1] + al[1] * LO_SCL,
                                         ah[2] + al[2] * LO_SCL, ah[3] + al[3] * LO_SCL);
  }
  {
    float ah[4] = {0, 0, 0, 0}, al[4] = {0, 0, 0, 0};
    const uint4* WL = WloRZ + 4096 + tid;   // Uz groups
    uint4 cb[4];
#pragma unroll
    for (int i = 0; i < 4; i++) cb[i] = WL[i * 512];
#pragma unroll
    for (int g = 0; g < 8; g++) {
      uint4 cur = cb[g & 3];
      if (g < 4) cb[g & 3] = WL[(g + 4) * 512];
      uint2 x2h = *(const uint2*)&xh_ls[16 * q + 2 * g];
      uint2 x2l = *(const uint2*)&xl_ls[16 * q + 2 * g];
      DOT_J(wz, h2cast(x2h.x), h2cast(x2l.x), cur.x, cur.y, ah, al, 2 * g);
      DOT_J(wz, h2cast(x2h.y), h2cast(x2l.y), cur.z, cur.w, ah, al, 2 * g + 1);
    }
    *(float4*)&redZ[q][u0] = make_float4(ah[0] + al[0] * LO_SCL, ah[1] + al[1] * LO_SCL,
                                         ah[2] + al[2] * LO_SCL, ah[3] + al[3] * LO_SCL);
  }
}

// ---------------- kernel 2: recurrence, 1 block/batch, compensated fp16 ------------
__global__ __launch_bounds__(512, 2) void recurrent_kernel(
    const float* __restrict__ P, const unsigned* __restrict__ Wpk,
    const unsigned* __restrict__ WloH, const uint4* __restrict__ WloRZ,
    const int* __restrict__ dep, const int* __restrict__ mask,
    const float* __restrict__ init, float* __restrict__ out,
    float* __restrict__ buf_s, float* __restrict__ buf_pr, float* __restrict__ buf_pz)
{
  const int b = blockIdx.x;
  const int tid = threadIdx.x;
  const int q = tid >> 6;
  const int l = tid & 63;
  const int u0 = 4 * l;

  // hi weights in registers: [cc][j], col u0+cc, k-pair j of slice [32q,32q+32)
  half2_t wh[4][16], wr[4][16], wz[4][16];
  {
    const uint4* pw = (const uint4*)(Wpk + (size_t)tid * 192);
#pragma unroll
    for (int cc = 0; cc < 4; cc++) {
#pragma unroll
      for (int i = 0; i < 4; i++) {
        uint4 a = pw[(0 * 4 + cc) * 4 + i];
        wh[cc][4 * i + 0] = h2cast(a.x); wh[cc][4 * i + 1] = h2cast(a.y);
        wh[cc][4 * i + 2] = h2cast(a.z); wh[cc][4 * i + 3] = h2cast(a.w);
        uint4 r_ = pw[(1 * 4 + cc) * 4 + i];
        wr[cc][4 * i + 0] = h2cast(r_.x); wr[cc][4 * i + 1] = h2cast(r_.y);
        wr[cc][4 * i + 2] = h2cast(r_.z); wr[cc][4 * i + 3] = h2cast(r_.w);
        uint4 z_ = pw[(2 * 4 + cc) * 4 + i];
        wz[cc][4 * i + 0] = h2cast(z_.x); wz[cc][4 * i + 1] = h2cast(z_.y);
        wz[cc][4 * i + 2] = h2cast(z_.z); wz[cc][4 * i + 3] = h2cast(z_.w);
      }
    }
  }

  // LDS: 131072 + 8192 + 8192 + 2048 + 3072 + 3072 + 1024 + 512 + 3072 = 160256 B
  __shared__ unsigned uhlo[32768];
  __shared__ float redR[8][256];
  __shared__ float redZ[8][256];
  __shared__ unsigned rs2h[128], rs2l[128], hx2h[128], hx2l[128];
  __shared__ float hs_l[256], zs_l[256], xh_l[256];
  __shared__ float prev_h[256], prev_pr[256], prev_pz[256];
  __shared__ short eff[TN];
  __shared__ unsigned char mloc[TN];
  __shared__ unsigned short deploc[TN * 3];

  for (int i = tid; i < TN; i += 512) mloc[i] = (unsigned char)mask[b * TN + i];
  for (int i = tid; i < TN * 3; i += 512) deploc[i] = (unsigned short)dep[i];
  for (int i = tid; i < 32768; i += 512) uhlo[i] = WloH[i];
  if (tid < 256) { prev_h[tid] = 0.0f; prev_pr[tid] = 0.0f; prev_pz[tid] = 0.0f; }
  __syncthreads();

  const size_t outB = (size_t)b * TN * UN;
  const size_t pB   = (size_t)b * TN * NC;
  const size_t bufB = (size_t)b * SLOTS * UN;

  // prologue: initial states -> slots TN..TN+3 with projections
#pragma unroll 1
  for (int i = 0; i < 4; i++) {
    if (tid < 256) {
      float v = init[((size_t)i * BN + b) * UN + tid];
      buf_s[bufB + (size_t)(TN + i) * UN + tid] = v;
      _Float16 v16 = (_Float16)v;
      float vl = v - (float)v16;
      ((unsigned short*)rs2h)[tid] = __builtin_bit_cast(unsigned short, v16);
      ((unsigned short*)rs2l)[tid] = __builtin_bit_cast(unsigned short, (_Float16)vl);
    }
    __syncthreads();
    proj_rz(tid, q, u0, rs2h, rs2l, wr, wz, WloRZ, redR, redZ);
    __syncthreads();
    if (tid < 256) {
      float sr = 0.0f, sz = 0.0f;
#pragma unroll
      for (int qq = 0; qq < 8; qq++) { sr += redR[qq][tid]; sz += redZ[qq][tid]; }
      buf_pr[bufB + (size_t)(TN + i) * UN + tid] = sr;
      buf_pz[bufB + (size_t)(TN + i) * UN + tid] = sz;
    }
    __syncthreads();
  }

#pragma unroll 1
  for (int t = 0; t < TN; t++) {
    if (mloc[t] == 0) {
      if (tid < 256) out[outB + (size_t)t * UN + tid] = 0.0f;
      if (tid == 0) eff[t] = (t == 0) ? (short)-1 : eff[t - 1];
      __syncthreads();
      continue;
    }
    // ---- A: gather + gates + pack rs (hi/lo) ----
    if (tid < 256) {
      const int u = tid;
      float s0, s1, s2, s3, pr0, pr1, pr2, pr3, pz0, pz1, pz2, pz3;
      if (t == 0) {
        size_t a0 = bufB + (size_t)(TN + 0) * UN + u;
        size_t a1 = bufB + (size_t)(TN + 1) * UN + u;
        size_t a2 = bufB + (size_t)(TN + 2) * UN + u;
        size_t a3 = bufB + (size_t)(TN + 3) * UN + u;
        s0 = buf_s[a0]; pr0 = buf_pr[a0]; pz0 = buf_pz[a0];
        s1 = buf_s[a1]; pr1 = buf_pr[a1]; pz1 = buf_pz[a1];
        s2 = buf_s[a2]; pr2 = buf_pr[a2]; pz2 = buf_pz[a2];
        s3 = buf_s[a3]; pr3 = buf_pr[a3]; pz3 = buf_pz[a3];
      } else {
        s0 = prev_h[u]; pr0 = prev_pr[u]; pz0 = prev_pz[u];
        int e1 = eff[deploc[(t - 1) * 3 + 0]];
        int e2 = eff[deploc[(t - 1) * 3 + 1]];
        int e3 = eff[deploc[(t - 1) * 3 + 2]];
        if (e1 < 0) { s1 = 0; pr1 = 0; pz1 = 0; }
        else { size_t a = bufB + (size_t)e1 * UN + u; s1 = buf_s[a]; pr1 = buf_pr[a]; pz1 = buf_pz[a]; }
        if (e2 < 0) { s2 = 0; pr2 = 0; pz2 = 0; }
        else { size_t a = bufB + (size_t)e2 * UN + u; s2 = buf_s[a]; pr2 = buf_pr[a]; pz2 = buf_pz[a]; }
        if (e3 < 0) { s3 = 0; pr3 = 0; pz3 = 0; }
        else { size_t a = bufB + (size_t)e3 * UN + u; s3 = buf_s[a]; pr3 = buf_pr[a]; pz3 = buf_pz[a]; }
      }
      float xr = P[pB + (size_t)t * NC + u];
      float xz = P[pB + (size_t)t * NC + 256 + u];
      xh_l[u] = P[pB + (size_t)t * NC + 512 + u];
      float r0 = sigm(xr + pr0), r1 = sigm(xr + pr1), r2 = sigm(xr + pr2), r3 = sigm(xr + pr3);
      float rsv = r0 * s0 + r1 * s1 + r2 * s2 + r3 * s3;
      hs_l[u] = (s0 + s1) + (s2 + s3);
      zs_l[u] = sigm(xz + ((pz0 + pz1) + (pz2 + pz3)));
      _Float16 r16 = (_Float16)rsv;
      float rl = rsv - (float)r16;
      ((unsigned short*)rs2h)[u] = __builtin_bit_cast(unsigned short, r16);
      ((unsigned short*)rs2l)[u] = __builtin_bit_cast(unsigned short, (_Float16)rl);
    }
    __syncthreads();
    // ---- B: rs @ Uh (hi regs + fp16-lo from LDS, 3-term) ----
    {
      float ah[4] = {0, 0, 0, 0}, al[4] = {0, 0, 0, 0};
#pragma unroll
      for (int g = 0; g < 8; g++) {
        uint2 wa = *(const uint2*)&uhlo[(4 * g + 0) * 1024 + 2 * tid];
        uint2 wb = *(const uint2*)&uhlo[(4 * g + 1) * 1024 + 2 * tid];
        uint2 wc = *(const uint2*)&uhlo[(4 * g + 2) * 1024 + 2 * tid];
        uint2 wd = *(const uint2*)&uhlo[(4 * g + 3) * 1024 + 2 * tid];
        uint2 x2h = *(const uint2*)&rs2h[16 * q + 2 * g];
        uint2 x2l = *(const uint2*)&rs2l[16 * q + 2 * g];
        DOT_J_H(wh, h2cast(x2h.x), h2cast(x2l.x), wa, wb, ah, al, 2 * g);
        DOT_J_H(wh, h2cast(x2h.y), h2cast(x2l.y), wc, wd, ah, al, 2 * g + 1);
      }
      *(float4*)&redR[q][u0] = make_float4(ah[0] + al[0] * LO_SCL, ah[1] + al[1] * LO_SCL,
                                           ah[2] + al[2] * LO_SCL, ah[3] + al[3] * LO_SCL);
    }
    __syncthreads();
    // ---- C: h, output, pack h (hi/lo) ----
    if (tid < 256) {
      const int u = tid;
      float hh = 0.0f;
#pragma unroll
      for (int qq = 0; qq < 8; qq++) hh += redR[qq][u];
      float z = zs_l[u];
      float h = z * hs_l[u] * 0.25f + (1.0f - z) * tanh_fast(xh_l[u] + hh);
      prev_h[u] = h;
      out[outB + (size_t)t * UN + u] = h;
      buf_s[bufB + (size_t)t * UN + u] = h;
      _Float16 h16 = (_Float16)h;
      float hl = h - (float)h16;
      ((unsigned short*)hx2h)[u] = __builtin_bit_cast(unsigned short, h16);
      ((unsigned short*)hx2l)[u] = __builtin_bit_cast(unsigned short, (_Float16)hl);
    }
    __syncthreads();
    // ---- D: h @ Ur, h @ Uz (hi regs + bf8-lo streamed, 3-term) ----
    proj_rz(tid, q, u0, hx2h, hx2l, wr, wz, WloRZ, redR, redZ);
    __syncthreads();
    // ---- E: commit cached projections ----
    if (tid < 256) {
      const int u = tid;
      float pr = 0.0f, pz = 0.0f;
#pragma unroll
      for (int qq = 0; qq < 8; qq++) { pr += redR[qq][u]; pz += redZ[qq][u]; }
      prev_pr[u] = pr; prev_pz[u] = pz;
      size_t a = bufB + (size_t)t * UN + u;
      buf_pr[a] = pr; buf_pz[a] = pz;
    }
    if (tid == 0) eff[t] = (short)t;
    __syncthreads();
  }

  // epilogue: last_out, last_state
  if (tid < 256) {
    float lst = prev_h[tid];
    out[(size_t)BN * TN * UN + (size_t)b * UN + tid] = mloc[TN - 1] ? lst : 0.0f;
    out[(size_t)BN * TN * UN + (size_t)BN * UN + (size_t)b * UN + tid] = lst;
  }
}

extern "C" void kernel_launch(void* const* d_in, const int* in_sizes, int n_in,
                              void* d_out, int out_size, void* d_ws, size_t ws_size,
                              hipStream_t stream) {
  const float* inputs       = (const float*)d_in[0];
  const int*   dependencies = (const int*)d_in[1];
  const int*   mask         = (const int*)d_in[2];
  const float* initial      = (const float*)d_in[3];
  const float* Wz = (const float*)d_in[4];
  const float* Wr = (const float*)d_in[5];
  const float* Wh = (const float*)d_in[6];
  const float* Uz = (const float*)d_in[7];
  const float* Ur = (const float*)d_in[8];
  const float* Uh = (const float*)d_in[9];
  const float* bz = (const float*)d_in[10];
  const float* br = (const float*)d_in[11];
  const float* bh = (const float*)d_in[12];

  float* out = (float*)d_out;
  float* ws  = (float*)d_ws;

  float*    wcat    = ws;                                    // 196608 f
  float*    bias    = wcat + (size_t)DN * NC;                // 768 f
  float*    precomp = bias + NC;                             // 25165824 f
  unsigned* Wpk     = (unsigned*)(precomp + (size_t)BN * TN * NC);   // 98304 u32
  unsigned* WloH    = Wpk + 98304;                           // 32768 u32
  unsigned* WloRZ   = WloH + 32768;                          // 32768 u32
  float*    buf_s   = (float*)(WloRZ + 32768);               // B*SLOTS*256 each
  float*    buf_pr  = buf_s + (size_t)BN * SLOTS * UN;
  float*    buf_pz  = buf_pr + (size_t)BN * SLOTS * UN;

  build_wcat<<<(DN * NC + 255) / 256, 256, 0, stream>>>(Wr, Wz, Wh, br, bz, bh, wcat, bias);
  build_wpk<<<98304 / 256, 256, 0, stream>>>(Uh, Ur, Uz, Wpk);
  build_wlo<<<98304 / 256, 256, 0, stream>>>(Uh, Ur, Uz, WloH, (unsigned short*)WloRZ);
  gemm_xw<<<dim3(BN * TN / 64, NC / 64), 256, 0, stream>>>(inputs, wcat, bias, precomp);
  recurrent_kernel<<<BN, 512, 0, stream>>>(precomp, Wpk, WloH, (const uint4*)WloRZ,
                                           dependencies, mask, initial,
                                           out, buf_s, buf_pr, buf_pz);
}